// Round 5
// baseline (2815.456 us; speedup 1.0000x reference)
//
#include <hip/hip_runtime.h>
#include <hip/hip_bf16.h>
#include <math.h>

#define HID 256
#define CTXD 128
#define FEAT 512
#define NLAYER 4

typedef __hip_bfloat16 bf16;
typedef __attribute__((ext_vector_type(8))) short short8;
typedef __attribute__((ext_vector_type(4))) float floatx4;

__device__ __forceinline__ float bf2f(bf16 x) { return __bfloat162float(x); }
__device__ __forceinline__ bf16 f2bf(float x) { return __float2bfloat16(x); }
__device__ __forceinline__ float us2f(unsigned short u) {
    union { unsigned u; float f; } c; c.u = ((unsigned)u) << 16; return c.f;
}
__device__ __forceinline__ unsigned short f2us(float f) {
    bf16 b = f2bf(f); return *(unsigned short*)&b;
}

// async global->LDS, 16 B per lane; LDS dst = wave-uniform base + lane*16
__device__ __forceinline__ void glds16(const void* g, void* l) {
    __builtin_amdgcn_global_load_lds(
        (__attribute__((address_space(1))) void*)g,
        (__attribute__((address_space(3))) void*)l, 16, 0, 0);
}

// ===========================================================================
// CSR build: counting sort of edges by dst
// ===========================================================================
__global__ __launch_bounds__(256) void hist_kernel(const int* __restrict__ dst,
                                                   int* __restrict__ cnt, int E)
{
    int i = blockIdx.x * 256 + threadIdx.x;
    if (i < E) atomicAdd(&cnt[dst[i]], 1);
}

__global__ __launch_bounds__(256) void scan1_kernel(int* __restrict__ cnt,
                                                    int* __restrict__ bsum)
{
    __shared__ int sd[256];
    const int t = threadIdx.x;
    const int i = blockIdx.x * 256 + t;
    int v = cnt[i];
    sd[t] = v;
    __syncthreads();
    for (int o = 1; o < 256; o <<= 1) {
        int x = (t >= o) ? sd[t - o] : 0;
        __syncthreads();
        sd[t] += x;
        __syncthreads();
    }
    cnt[i] = sd[t] - v;
    if (t == 255) bsum[blockIdx.x] = sd[255];
}

__global__ void scan2_kernel(int* __restrict__ bsum)  // 1 block, 512 threads
{
    __shared__ int sd[512];
    const int t = threadIdx.x;
    int v = bsum[t];
    sd[t] = v;
    __syncthreads();
    for (int o = 1; o < 512; o <<= 1) {
        int x = (t >= o) ? sd[t - o] : 0;
        __syncthreads();
        sd[t] += x;
        __syncthreads();
    }
    bsum[t] = sd[t] - v;
}

__global__ __launch_bounds__(256) void scan3_kernel(int* __restrict__ cnt,
                                                    const int* __restrict__ bsum)
{
    int i = blockIdx.x * 256 + threadIdx.x;
    cnt[i] += bsum[blockIdx.x];
}

__global__ __launch_bounds__(256) void scatter_perm_kernel(
    const int* __restrict__ dst, int* __restrict__ cursor,
    int* __restrict__ perm, int E)
{
    int i = blockIdx.x * 256 + threadIdx.x;
    if (i < E) {
        int p = atomicAdd(&cursor[dst[i]], 1);
        perm[p] = i;
    }
}
// after scatter: cursor[v] == rowptr[v+1]

// ===========================================================================
// Weight image: img[l][kt][n][kc] = bf16(W[l][kt*32+kc][n]) (zero-pad k>=K)
// ===========================================================================
__global__ __launch_bounds__(256)
void build_wimg_kernel(const float* __restrict__ W, bf16* __restrict__ img,
                       int K, int KT, int L)
{
    long idx = (long)blockIdx.x * 256 + threadIdx.x;
    long tot = (long)L * KT * 8192;
    if (idx >= tot) return;
    int l  = (int)(idx / ((long)KT * 8192));
    int r  = (int)(idx % ((long)KT * 8192));
    int kt = r >> 13;
    int r2 = r & 8191;
    int n  = r2 >> 5;
    int kc = r2 & 31;
    int k  = kt * 32 + kc;
    float v = (k < K) ? W[((long)l * K + k) * HID + n] : 0.f;
    img[idx] = f2bf(v);
}

// ===========================================================================
// Message GEMM (MFMA bf16): 128x256 tile, K=512, rows = CSR-permuted edges.
// A = [ h[src] (glds gather) || relu(ef@We+be) recomputed ], B from Wimg glds.
// ===========================================================================
__global__ __launch_bounds__(256)
void msg_gemm2(const bf16* __restrict__ h_, const float* __restrict__ ef,
               const float* __restrict__ We, const float* __restrict__ be,
               const int* __restrict__ src, const int* __restrict__ perm,
               const float* __restrict__ W, const bf16* __restrict__ Wimg,
               const float* __restrict__ bias, bf16* __restrict__ mout)
{
    __shared__ __align__(16) short As[128 * 32];
    __shared__ __align__(16) short Bs[256 * 32];
    __shared__ int   srcL[128];
    __shared__ int   edgeL[128];
    __shared__ float efL[128][9];

    const int  t  = threadIdx.x;
    const long bm = (long)blockIdx.x * 128;

    if (t < 128) {
        int eg = perm[bm + t];
        edgeL[t] = eg;
        srcL[t]  = src[eg];
    }
    __syncthreads();
    for (int i = t; i < 128 * 9; i += 256) {
        int r = i / 9, qq = i % 9;
        efL[r][qq] = ef[(long)edgeL[r] * 9 + qq];
    }
    __syncthreads();

    floatx4 acc[4][8];
#pragma unroll
    for (int i = 0; i < 4; ++i)
#pragma unroll
        for (int j = 0; j < 8; ++j) acc[i][j] = (floatx4){0.f, 0.f, 0.f, 0.f};

    const int w = t >> 6, lane = t & 63;
    const int fr = lane & 15, q = lane >> 4;
    const int wm = (w & 1) * 64, wn = (w >> 1) * 128;
    const int i4 = lane >> 2, kq = lane & 3;

    for (int kt = 0; kt < 16; ++kt) {
        const int k0 = kt * 32;
        if (k0 < HID) {
            // ---- A: h[src] gather via global_load_lds (16B/lane) ----
#pragma unroll
            for (int cc = 0; cc < 2; ++cc) {
                const int rowb = (cc * 4 + w) * 16;
                const int row  = rowb + i4;
                const short* gp = (const short*)h_ +
                                  ((long)srcL[row] * HID + k0 + kq * 8);
                const int loff = __builtin_amdgcn_readfirstlane(rowb * 64);
                glds16(gp, (char*)As + loff);
            }
        } else {
            // ---- A: recompute e = relu(ef@We+be), bank-aware ds_write_b128 ----
#pragma unroll
            for (int cc = 0; cc < 2; ++cc) {
                const int slot = t + cc * 256;
                const int row  = slot >> 2;
                const int kg   = slot & 3;
                const int kc   = k0 - HID + kg * 8;
                float s[8];
#pragma unroll
                for (int j = 0; j < 8; ++j) s[j] = be[kc + j];
#pragma unroll
                for (int qq = 0; qq < 9; ++qq) {
                    const float efv = efL[row][qq];
#pragma unroll
                    for (int j = 0; j < 8; ++j)
                        s[j] = fmaf(efv, We[qq * HID + kc + j], s[j]);
                }
                short8 pk;
#pragma unroll
                for (int j = 0; j < 8; ++j) pk[j] = (short)f2us(fmaxf(s[j], 0.f));
                *(short8*)&As[row * 32 + kg * 8] = pk;
            }
        }
        // ---- B staging ----
        if (Wimg) {
            const short* base = (const short*)Wimg + (long)kt * 8192;
#pragma unroll
            for (int j = 0; j < 4; ++j) {
                const int chunk = w * 4 + j;
                const short* gp = base + chunk * 512 + lane * 8;
                const int loff = __builtin_amdgcn_readfirstlane(chunk * 1024);
                glds16(gp, (char*)Bs + loff);
            }
        } else {
#pragma unroll
            for (int cc = 0; cc < 4; ++cc) {
                const int slot = t + cc * 256;
                const int n    = slot >> 2;
                const int kg   = slot & 3;
                const int kk   = k0 + kg * 8;
                short8 pk;
#pragma unroll
                for (int j = 0; j < 8; ++j)
                    pk[j] = (short)f2us(W[(long)(kk + j) * HID + n]);
                *(short8*)&Bs[n * 32 + kg * 8] = pk;
            }
        }
        __syncthreads();
        short8 af[4], bf8[8];
#pragma unroll
        for (int mt = 0; mt < 4; ++mt)
            af[mt] = *(const short8*)&As[(wm + mt * 16 + fr) * 32 + q * 8];
#pragma unroll
        for (int nt = 0; nt < 8; ++nt)
            bf8[nt] = *(const short8*)&Bs[(wn + nt * 16 + fr) * 32 + q * 8];
#pragma unroll
        for (int mt = 0; mt < 4; ++mt)
#pragma unroll
            for (int nt = 0; nt < 8; ++nt)
                acc[mt][nt] = __builtin_amdgcn_mfma_f32_16x16x32_bf16(
                    af[mt], bf8[nt], acc[mt][nt], 0, 0, 0);
        __syncthreads();
    }

#pragma unroll
    for (int nt = 0; nt < 8; ++nt) {
        const int col = wn + nt * 16 + fr;
        const float bv = bias[col];
#pragma unroll
        for (int mt = 0; mt < 4; ++mt)
#pragma unroll
            for (int reg = 0; reg < 4; ++reg) {
                const long row = bm + wm + mt * 16 + q * 4 + reg;
                mout[row * HID + col] = f2bf(fmaxf(acc[mt][nt][reg] + bv, 0.f));
            }
    }
}

// ===========================================================================
// Update GEMM (MFMA bf16): 128x256 tile, K=256, rows = nodes.
// A = CSR segment-sum of mbuf; B from Wimg glds.
// Epilogue: v = h_old + relu(acc+bias); h = LN(v) fused (full row in block).
// ===========================================================================
__global__ __launch_bounds__(256)
void upd_gemm2(const bf16* __restrict__ mbuf, const int* __restrict__ cursor,
               const float* __restrict__ W, const bf16* __restrict__ Wimg,
               const float* __restrict__ bias,
               const float* __restrict__ lng, const float* __restrict__ lnb,
               bf16* __restrict__ h_)
{
    __shared__ __align__(16) short As[128 * 32];
    __shared__ __align__(16) short Bs[256 * 32];
    __shared__ int   rpL[129];
    __shared__ float redS[128][2];
    __shared__ float redS2[128][2];

    const int  t  = threadIdx.x;
    const long bm = (long)blockIdx.x * 128;

    if (t < 128) rpL[t + 1] = cursor[bm + t];
    if (t == 0)  rpL[0] = (bm == 0) ? 0 : cursor[bm - 1];
    __syncthreads();

    floatx4 acc[4][8];
#pragma unroll
    for (int i = 0; i < 4; ++i)
#pragma unroll
        for (int j = 0; j < 8; ++j) acc[i][j] = (floatx4){0.f, 0.f, 0.f, 0.f};

    const int w = t >> 6, lane = t & 63;
    const int fr = lane & 15, q = lane >> 4;
    const int wm = (w & 1) * 64, wn = (w >> 1) * 128;

    for (int kt = 0; kt < 8; ++kt) {
        const int k0 = kt * 32;
        // ---- A: CSR segment-sum of m (each (edge,kc) read exactly once) ----
#pragma unroll
        for (int cc = 0; cc < 2; ++cc) {
            const int slot = t + cc * 256;
            const int row  = slot >> 2;
            const int kg   = slot & 3;
            const int kk   = k0 + kg * 8;
            float s[8] = {0.f, 0.f, 0.f, 0.f, 0.f, 0.f, 0.f, 0.f};
            const int j1 = rpL[row + 1];
            for (int j = rpL[row]; j < j1; ++j) {
                const short8 mv = *(const short8*)((const short*)mbuf +
                                                   ((long)j * HID + kk));
#pragma unroll
                for (int x = 0; x < 8; ++x) s[x] += us2f((unsigned short)mv[x]);
            }
            short8 pk;
#pragma unroll
            for (int x = 0; x < 8; ++x) pk[x] = (short)f2us(s[x]);
            *(short8*)&As[row * 32 + kg * 8] = pk;
        }
        // ---- B staging ----
        if (Wimg) {
            const short* base = (const short*)Wimg + (long)kt * 8192;
#pragma unroll
            for (int j = 0; j < 4; ++j) {
                const int chunk = w * 4 + j;
                const short* gp = base + chunk * 512 + lane * 8;
                const int loff = __builtin_amdgcn_readfirstlane(chunk * 1024);
                glds16(gp, (char*)Bs + loff);
            }
        } else {
#pragma unroll
            for (int cc = 0; cc < 4; ++cc) {
                const int slot = t + cc * 256;
                const int n    = slot >> 2;
                const int kg   = slot & 3;
                const int kk   = k0 + kg * 8;
                short8 pk;
#pragma unroll
                for (int j = 0; j < 8; ++j)
                    pk[j] = (short)f2us(W[(long)(kk + j) * HID + n]);
                *(short8*)&Bs[n * 32 + kg * 8] = pk;
            }
        }
        __syncthreads();
        short8 af[4], bf8[8];
#pragma unroll
        for (int mt = 0; mt < 4; ++mt)
            af[mt] = *(const short8*)&As[(wm + mt * 16 + fr) * 32 + q * 8];
#pragma unroll
        for (int nt = 0; nt < 8; ++nt)
            bf8[nt] = *(const short8*)&Bs[(wn + nt * 16 + fr) * 32 + q * 8];
#pragma unroll
        for (int mt = 0; mt < 4; ++mt)
#pragma unroll
            for (int nt = 0; nt < 8; ++nt)
                acc[mt][nt] = __builtin_amdgcn_mfma_f32_16x16x32_bf16(
                    af[mt], bf8[nt], acc[mt][nt], 0, 0, 0);
        __syncthreads();
    }

    // ---- fused residual + LayerNorm epilogue ----
    const int half = wn >> 7;
#pragma unroll
    for (int mt = 0; mt < 4; ++mt)
#pragma unroll
        for (int reg = 0; reg < 4; ++reg) {
            const int  lrow = wm + mt * 16 + q * 4 + reg;
            const long row  = bm + lrow;
            float ps = 0.f, ps2 = 0.f;
#pragma unroll
            for (int nt = 0; nt < 8; ++nt) {
                const int col = wn + nt * 16 + fr;
                float v = bf2f(h_[row * HID + col]) +
                          fmaxf(acc[mt][nt][reg] + bias[col], 0.f);
                acc[mt][nt][reg] = v;
                ps  += v;
                ps2 += v * v;
            }
#pragma unroll
            for (int m = 1; m < 16; m <<= 1) {
                ps  += __shfl_xor(ps, m);
                ps2 += __shfl_xor(ps2, m);
            }
            if (fr == 0) { redS[lrow][half] = ps; redS2[lrow][half] = ps2; }
        }
    __syncthreads();
#pragma unroll
    for (int mt = 0; mt < 4; ++mt)
#pragma unroll
        for (int reg = 0; reg < 4; ++reg) {
            const int  lrow = wm + mt * 16 + q * 4 + reg;
            const long row  = bm + lrow;
            const float ts  = redS[lrow][0] + redS[lrow][1];
            const float ts2 = redS2[lrow][0] + redS2[lrow][1];
            const float mu  = ts * (1.f / 256.f);
            const float var = ts2 * (1.f / 256.f) - mu * mu;
            const float rs  = rsqrtf(var + 1e-5f);
#pragma unroll
            for (int nt = 0; nt < 8; ++nt) {
                const int col = wn + nt * 16 + fr;
                const float y = (acc[mt][nt][reg] - mu) * rs * lng[col] + lnb[col];
                h_[row * HID + col] = f2bf(y);
            }
        }
}

// ===========================================================================
// Node encoder (MFMA bf16): h = relu(nf @ Wn + bn), K padded 69->96
// ===========================================================================
__global__ __launch_bounds__(256)
void enc_gemm2(const float* __restrict__ nf, const bf16* __restrict__ Wimg,
               const float* __restrict__ bias, bf16* __restrict__ h_)
{
    __shared__ __align__(16) short As[128 * 32];
    __shared__ __align__(16) short Bs[256 * 32];

    const int  t  = threadIdx.x;
    const long bm = (long)blockIdx.x * 128;

    floatx4 acc[4][8];
#pragma unroll
    for (int i = 0; i < 4; ++i)
#pragma unroll
        for (int j = 0; j < 8; ++j) acc[i][j] = (floatx4){0.f, 0.f, 0.f, 0.f};

    const int w = t >> 6, lane = t & 63;
    const int fr = lane & 15, q = lane >> 4;
    const int wm = (w & 1) * 64, wn = (w >> 1) * 128;

    for (int kt = 0; kt < 3; ++kt) {
        const int k0 = kt * 32;
#pragma unroll
        for (int cc = 0; cc < 2; ++cc) {
            const int slot = t + cc * 256;
            const int row  = slot >> 2;
            const int kg   = slot & 3;
            const int kk   = k0 + kg * 8;
            short8 pk;
#pragma unroll
            for (int j = 0; j < 8; ++j) {
                const int k = kk + j;
                pk[j] = (short)f2us((k < 69) ? nf[(bm + row) * 69 + k] : 0.f);
            }
            *(short8*)&As[row * 32 + kg * 8] = pk;
        }
        const short* base = (const short*)Wimg + (long)kt * 8192;
#pragma unroll
        for (int j = 0; j < 4; ++j) {
            const int chunk = w * 4 + j;
            const short* gp = base + chunk * 512 + lane * 8;
            const int loff = __builtin_amdgcn_readfirstlane(chunk * 1024);
            glds16(gp, (char*)Bs + loff);
        }
        __syncthreads();
        short8 af[4], bf8[8];
#pragma unroll
        for (int mt = 0; mt < 4; ++mt)
            af[mt] = *(const short8*)&As[(wm + mt * 16 + fr) * 32 + q * 8];
#pragma unroll
        for (int nt = 0; nt < 8; ++nt)
            bf8[nt] = *(const short8*)&Bs[(wn + nt * 16 + fr) * 32 + q * 8];
#pragma unroll
        for (int mt = 0; mt < 4; ++mt)
#pragma unroll
            for (int nt = 0; nt < 8; ++nt)
                acc[mt][nt] = __builtin_amdgcn_mfma_f32_16x16x32_bf16(
                    af[mt], bf8[nt], acc[mt][nt], 0, 0, 0);
        __syncthreads();
    }

#pragma unroll
    for (int nt = 0; nt < 8; ++nt) {
        const int col = wn + nt * 16 + fr;
        const float bv = bias[col];
#pragma unroll
        for (int mt = 0; mt < 4; ++mt)
#pragma unroll
            for (int reg = 0; reg < 4; ++reg) {
                const long row = bm + wm + mt * 16 + q * 4 + reg;
                h_[row * HID + col] = f2bf(fmaxf(acc[mt][nt][reg] + bv, 0.f));
            }
    }
}

// ===========================================================================
// SIMT fp32 GEMM (FiLM / head / encoder fallback)
// ===========================================================================
struct PlainF32 {
    const float* A; int lda;
    __device__ float operator()(int r, int k) const { return A[(long)r * lda + k]; }
};
struct CtxF32 {
    const float* ctx; const int* pid;
    __device__ float operator()(int r, int k) const {
        return ctx[(long)pid[r] * CTXD + k];
    }
};
struct StoreF32 {
    float* C; int ldc; int relu;
    __device__ void operator()(int r, int c, const float* v) const {
        float4 o;
        o.x = v[0]; o.y = v[1]; o.z = v[2]; o.w = v[3];
        if (relu) {
            o.x = fmaxf(o.x, 0.f); o.y = fmaxf(o.y, 0.f);
            o.z = fmaxf(o.z, 0.f); o.w = fmaxf(o.w, 0.f);
        }
        *(float4*)&C[(long)r * ldc + c] = o;
    }
};
struct StoreBf16Relu {
    bf16* C;
    __device__ void operator()(int r, int c, const float* v) const {
        bf16 tmp[4];
#pragma unroll
        for (int j = 0; j < 4; ++j) tmp[j] = f2bf(fmaxf(v[j], 0.f));
        *(ushort4*)&C[(long)r * HID + c] = *(const ushort4*)tmp;
    }
};

template <typename Loader, typename Epi>
__global__ __launch_bounds__(256)
void gemm_tiled(Loader loader, const float* __restrict__ W,
                const float* __restrict__ bias, Epi epi, int M, int K, int Nc)
{
    constexpr int BM = 64, BN = 64, BK = 16;
    __shared__ __align__(16) float As[BK][BM + 4];
    __shared__ __align__(16) float Ws[BK][BN];

    const int bm = blockIdx.x * BM;
    const int bn = blockIdx.y * BN;
    const int t  = threadIdx.x;
    const int arow = t >> 2, akq = (t & 3) * 4;
    const int wn = t & 63, wk0 = t >> 6;
    const int tx = t & 15, ty = t >> 4;

    float acc[4][4] = {};
    const int ntiles = (K + BK - 1) / BK;
    for (int kt = 0; kt < ntiles; ++kt) {
        const int k0 = kt * BK;
#pragma unroll
        for (int i = 0; i < 4; ++i) {
            int k = k0 + akq + i;
            As[akq + i][arow] = (k < K) ? loader(bm + arow, k) : 0.f;
        }
#pragma unroll
        for (int i = 0; i < 4; ++i) {
            int kr = wk0 + i * 4;
            int k  = k0 + kr;
            Ws[kr][wn] = (k < K) ? W[(long)k * Nc + bn + wn] : 0.f;
        }
        __syncthreads();
#pragma unroll
        for (int kk = 0; kk < BK; ++kk) {
            float4 a = *(const float4*)&As[kk][ty * 4];
            float4 b = *(const float4*)&Ws[kk][tx * 4];
            float av[4] = {a.x, a.y, a.z, a.w};
            float bv[4] = {b.x, b.y, b.z, b.w};
#pragma unroll
            for (int i = 0; i < 4; ++i)
#pragma unroll
                for (int j = 0; j < 4; ++j) acc[i][j] += av[i] * bv[j];
        }
        __syncthreads();
    }
#pragma unroll
    for (int i = 0; i < 4; ++i) {
        const int row = bm + ty * 4 + i;
        const int col = bn + tx * 4;
        float v[4];
#pragma unroll
        for (int j = 0; j < 4; ++j) v[j] = acc[i][j] + bias[col + j];
        epi(row, col, v);
    }
}

// ===========================================================================
// LN (fp32, FiLM) / readout / FiLM / head
// ===========================================================================
__global__ __launch_bounds__(256)
void ln_f32_relu_kernel(float* __restrict__ x, const float* __restrict__ g,
                        const float* __restrict__ bb)
{
    const long row = blockIdx.x;
    const int  j   = threadIdx.x;
    float v = x[row * HID + j];
    float s = v, s2 = v * v;
#pragma unroll
    for (int o = 32; o > 0; o >>= 1) {
        s  += __shfl_down(s, o);
        s2 += __shfl_down(s2, o);
    }
    __shared__ float red[2][4];
    const int wid = j >> 6, lane = j & 63;
    if (lane == 0) { red[0][wid] = s; red[1][wid] = s2; }
    __syncthreads();
    float ts  = red[0][0] + red[0][1] + red[0][2] + red[0][3];
    float ts2 = red[1][0] + red[1][1] + red[1][2] + red[1][3];
    float mu  = ts * (1.f / 256.f);
    float var = ts2 * (1.f / 256.f) - mu * mu;
    float y = (v - mu) * rsqrtf(var + 1e-5f) * g[j] + bb[j];
    x[row * HID + j] = fmaxf(y, 0.f);
}

__device__ int lower_bound_i(const int* __restrict__ arr, int n, int val)
{
    int lo = 0, hi = n;
    while (lo < hi) {
        int mid = (lo + hi) >> 1;
        if (arr[mid] < val) lo = mid + 1; else hi = mid;
    }
    return lo;
}

__global__ __launch_bounds__(256)
void readout_kernel(const bf16* __restrict__ h, const int* __restrict__ b,
                    float* __restrict__ gout, int Nn)
{
    const int gidx = blockIdx.x;
    const int j    = threadIdx.x;
    const int lo   = lower_bound_i(b, Nn, gidx);
    const int hi   = lower_bound_i(b, Nn, gidx + 1);
    float s = 0.f, mx = -INFINITY;
    for (int n = lo; n < hi; ++n) {
        float v = bf2f(h[(long)n * HID + j]);
        s += v;
        mx = fmaxf(mx, v);
    }
    const int cnt = hi - lo;
    gout[(long)gidx * FEAT + j]       = s / fmaxf((float)cnt, 1.f);
    gout[(long)gidx * FEAT + HID + j] = (cnt > 0) ? mx : 0.f;
}

__global__ __launch_bounds__(256)
void film_mod_kernel(const float* __restrict__ gamma, float* __restrict__ g,
                     const float* __restrict__ beta, int n)
{
    int i = blockIdx.x * 256 + threadIdx.x;
    if (i < n) g[i] = gamma[i] * g[i] + beta[i];
}

__global__ __launch_bounds__(256)
void final_dot_kernel(const float* __restrict__ ph, const float* __restrict__ w,
                      const float* __restrict__ b2, float* __restrict__ out)
{
    const int row  = blockIdx.x * 4 + (threadIdx.x >> 6);
    const int lane = threadIdx.x & 63;
    float s = 0.f;
#pragma unroll
    for (int k = lane; k < HID; k += 64)
        s += ph[(long)row * HID + k] * w[k];
#pragma unroll
    for (int o = 32; o > 0; o >>= 1) s += __shfl_down(s, o);
    if (lane == 0) out[row] = s + b2[0];
}

__global__ void diag_out_kernel(float* out, int n, float wsmb)
{
    int i = blockIdx.x * 256 + threadIdx.x;
    if (i < n) out[i] = (i == 0) ? wsmb : 0.f;
}

// ===========================================================================
// launcher
// ===========================================================================
extern "C" void kernel_launch(void* const* d_in, const int* in_sizes, int n_in,
                              void* d_out, int out_size, void* d_ws, size_t ws_size,
                              hipStream_t stream)
{
    const int N = 131072, E = 262144, B = 4096;

    const float* nf   = (const float*)d_in[0];
    const int*   ei   = (const int*)  d_in[1];
    const float* ef   = (const float*)d_in[2];
    const int*   bidx = (const int*)  d_in[3];
    const int*   pid  = (const int*)  d_in[4];
    const float* Wn   = (const float*)d_in[5];
    const float* bn   = (const float*)d_in[6];
    const float* We   = (const float*)d_in[7];
    const float* be   = (const float*)d_in[8];
    const float* Wm   = (const float*)d_in[9];
    const float* bm   = (const float*)d_in[10];
    const float* Wu   = (const float*)d_in[11];
    const float* bu   = (const float*)d_in[12];
    const float* lng  = (const float*)d_in[13];
    const float* lnb  = (const float*)d_in[14];
    const float* ctx  = (const float*)d_in[15];
    const float* gW1  = (const float*)d_in[16];
    const float* gb1  = (const float*)d_in[17];
    const float* glng = (const float*)d_in[18];
    const float* glnb = (const float*)d_in[19];
    const float* gW2  = (const float*)d_in[20];
    const float* gb2  = (const float*)d_in[21];
    const float* bW1  = (const float*)d_in[22];
    const float* bb1  = (const float*)d_in[23];
    const float* blng = (const float*)d_in[24];
    const float* blnb = (const float*)d_in[25];
    const float* bW2  = (const float*)d_in[26];
    const float* bb2  = (const float*)d_in[27];
    const float* pW1  = (const float*)d_in[28];
    const float* pb1  = (const float*)d_in[29];
    const float* pW2  = (const float*)d_in[30];
    const float* pb2  = (const float*)d_in[31];

    const int* src = ei;
    const int* dst = ei + E;
    float* out = (float*)d_out;

    const size_t hB    = (size_t)N * HID * sizeof(bf16);   //  64 MiB
    const size_t mB    = (size_t)E * HID * sizeof(bf16);   // 128 MiB
    const size_t curB  = (size_t)N * 4;                    // 512 KiB
    const size_t permB = (size_t)E * 4;                    //   1 MiB
    const size_t bsumB = 2048 * 4;
    const size_t wmImgB = (size_t)NLAYER * 16 * 8192 * 2;  //   1 MiB
    const size_t wuImgB = (size_t)NLAYER * 8  * 8192 * 2;  // 512 KiB
    const size_t wnImgB = (size_t)3 * 8192 * 2;            //  48 KiB

    const size_t needBase = hB + mB + curB + permB + bsumB;       // ~193.5 MiB
    const size_t needFull = needBase + wmImgB + wuImgB + wnImgB;  // ~195.1 MiB

    if (ws_size < needBase) {
        diag_out_kernel<<<dim3((B + 255) / 256), dim3(256), 0, stream>>>(
            out, B, (float)(ws_size >> 20));
        return;
    }
    const bool haveImg = ws_size >= needFull;

    char* p = (char*)d_ws;
    bf16* h      = (bf16*)p;  p += hB;
    bf16* mbuf   = (bf16*)p;  p += mB;
    int*  cursor = (int*)p;   p += curB;
    int*  perm   = (int*)p;   p += permB;
    int*  bsum   = (int*)p;   p += bsumB;
    bf16* wmImg = nullptr; bf16* wuImg = nullptr; bf16* wnImg = nullptr;
    if (haveImg) {
        wmImg = (bf16*)p; p += wmImgB;
        wuImg = (bf16*)p; p += wuImgB;
        wnImg = (bf16*)p; p += wnImgB;
    }

    // FiLM scratch aliases mbuf (dead after layers)
    float* gbuf  = (float*)mbuf;            // B*512
    float* t1    = gbuf  + (long)B * FEAT;  // B*256
    float* t2    = t1    + (long)B * HID;   // B*256
    float* gamma = t2    + (long)B * HID;   // B*512
    float* beta  = gamma + (long)B * FEAT;  // B*512
    float* ph    = beta  + (long)B * FEAT;  // B*256

    dim3 blk(256);

    // --- CSR build ---
    hipMemsetAsync(cursor, 0, curB, stream);
    hist_kernel<<<dim3(E / 256), blk, 0, stream>>>(dst, cursor, E);
    scan1_kernel<<<dim3(N / 256), blk, 0, stream>>>(cursor, bsum);
    scan2_kernel<<<dim3(1), dim3(512), 0, stream>>>(bsum);
    scan3_kernel<<<dim3(N / 256), blk, 0, stream>>>(cursor, bsum);
    scatter_perm_kernel<<<dim3(E / 256), blk, 0, stream>>>(dst, cursor, perm, E);

    // --- weight images (bf16, LDS-image layout) ---
    if (haveImg) {
        build_wimg_kernel<<<dim3((NLAYER * 16 * 8192 + 255) / 256), blk, 0, stream>>>(
            Wm, wmImg, 2 * HID, 16, NLAYER);
        build_wimg_kernel<<<dim3((NLAYER * 8 * 8192 + 255) / 256), blk, 0, stream>>>(
            Wu, wuImg, HID, 8, NLAYER);
        build_wimg_kernel<<<dim3((3 * 8192 + 255) / 256), blk, 0, stream>>>(
            Wn, wnImg, 69, 3, 1);
    }

    // --- node encoder ---
    if (haveImg) {
        enc_gemm2<<<dim3(N / 128), blk, 0, stream>>>(nf, wnImg, bn, h);
    } else {
        gemm_tiled<<<dim3(N / 64, HID / 64), blk, 0, stream>>>(
            PlainF32{nf, 69}, Wn, bn, StoreBf16Relu{h}, N, 69, HID);
    }

    // --- message-passing layers ---
    for (int l = 0; l < NLAYER; ++l) {
        const float* Wml  = Wm  + (long)l * 2 * HID * HID;
        const float* bml  = bm  + (long)l * HID;
        const float* Wul  = Wu  + (long)l * HID * HID;
        const float* bul  = bu  + (long)l * HID;
        const float* lngl = lng + (long)l * HID;
        const float* lnbl = lnb + (long)l * HID;
        const bf16* wmI = haveImg ? wmImg + (long)l * 16 * 8192 : nullptr;
        const bf16* wuI = haveImg ? wuImg + (long)l * 8 * 8192 : nullptr;

        msg_gemm2<<<dim3(E / 128), blk, 0, stream>>>(
            h, ef, We, be, src, perm, Wml, wmI, bml, mbuf);
        upd_gemm2<<<dim3(N / 128), blk, 0, stream>>>(
            mbuf, cursor, Wul, wuI, bul, lngl, lnbl, h);
    }

    // --- readout ---
    readout_kernel<<<dim3(B), blk, 0, stream>>>(h, bidx, gbuf, N);

    // --- FiLM gamma / beta ---
    gemm_tiled<<<dim3(B / 64, HID / 64), blk, 0, stream>>>(
        CtxF32{ctx, pid}, gW1, gb1, StoreF32{t1, HID, 0}, B, CTXD, HID);
    ln_f32_relu_kernel<<<dim3(B), blk, 0, stream>>>(t1, glng, glnb);
    gemm_tiled<<<dim3(B / 64, FEAT / 64), blk, 0, stream>>>(
        PlainF32{t1, HID}, gW2, gb2, StoreF32{gamma, FEAT, 0}, B, HID, FEAT);

    gemm_tiled<<<dim3(B / 64, HID / 64), blk, 0, stream>>>(
        CtxF32{ctx, pid}, bW1, bb1, StoreF32{t2, HID, 0}, B, CTXD, HID);
    ln_f32_relu_kernel<<<dim3(B), blk, 0, stream>>>(t2, blng, blnb);
    gemm_tiled<<<dim3(B / 64, FEAT / 64), blk, 0, stream>>>(
        PlainF32{t2, HID}, bW2, bb2, StoreF32{beta, FEAT, 0}, B, HID, FEAT);

    // --- FiLM modulation + head ---
    film_mod_kernel<<<dim3((B * FEAT + 255) / 256), blk, 0, stream>>>(
        gamma, gbuf, beta, B * FEAT);
    gemm_tiled<<<dim3(B / 64, HID / 64), blk, 0, stream>>>(
        PlainF32{gbuf, FEAT}, pW1, pb1, StoreF32{ph, HID, 1}, B, FEAT, HID);
    final_dot_kernel<<<dim3(B / 4), blk, 0, stream>>>(ph, pW2, pb2, out);
}

// Round 6
// 2003.708 us; speedup vs baseline: 1.4051x; 1.4051x over previous
//
#include <hip/hip_runtime.h>
#include <hip/hip_bf16.h>
#include <math.h>

#define HID 256
#define CTXD 128
#define FEAT 512
#define NLAYER 4

// LDS slot swizzle: row stride is 32 shorts (64 B); rows 2 apart alias banks,
// so XOR the 16B k-group slot with (row>>1)&3 -> worst case 2-way (free, m136).
#define SW(n) (((n) >> 1) & 3)

typedef __hip_bfloat16 bf16;
typedef __attribute__((ext_vector_type(8))) short short8;
typedef __attribute__((ext_vector_type(4))) float floatx4;

__device__ __forceinline__ float bf2f(bf16 x) { return __bfloat162float(x); }
__device__ __forceinline__ bf16 f2bf(float x) { return __float2bfloat16(x); }
__device__ __forceinline__ float us2f(unsigned short u) {
    union { unsigned u; float f; } c; c.u = ((unsigned)u) << 16; return c.f;
}
__device__ __forceinline__ unsigned short f2us(float f) {
    bf16 b = f2bf(f); return *(unsigned short*)&b;
}

// async global->LDS, 16 B/lane, COALESCED addresses only (wave-uniform LDS base)
__device__ __forceinline__ void glds16(const void* g, void* l) {
    __builtin_amdgcn_global_load_lds(
        (__attribute__((address_space(1))) void*)g,
        (__attribute__((address_space(3))) void*)l, 16, 0, 0);
}

// ===========================================================================
// CSR build: counting sort of edges by dst
// ===========================================================================
__global__ __launch_bounds__(256) void hist_kernel(const int* __restrict__ dst,
                                                   int* __restrict__ cnt, int E)
{
    int i = blockIdx.x * 256 + threadIdx.x;
    if (i < E) atomicAdd(&cnt[dst[i]], 1);
}

__global__ __launch_bounds__(256) void scan1_kernel(int* __restrict__ cnt,
                                                    int* __restrict__ bsum)
{
    __shared__ int sd[256];
    const int t = threadIdx.x;
    const int i = blockIdx.x * 256 + t;
    int v = cnt[i];
    sd[t] = v;
    __syncthreads();
    for (int o = 1; o < 256; o <<= 1) {
        int x = (t >= o) ? sd[t - o] : 0;
        __syncthreads();
        sd[t] += x;
        __syncthreads();
    }
    cnt[i] = sd[t] - v;
    if (t == 255) bsum[blockIdx.x] = sd[255];
}

__global__ void scan2_kernel(int* __restrict__ bsum)  // 1 block, 512 threads
{
    __shared__ int sd[512];
    const int t = threadIdx.x;
    int v = bsum[t];
    sd[t] = v;
    __syncthreads();
    for (int o = 1; o < 512; o <<= 1) {
        int x = (t >= o) ? sd[t - o] : 0;
        __syncthreads();
        sd[t] += x;
        __syncthreads();
    }
    bsum[t] = sd[t] - v;
}

__global__ __launch_bounds__(256) void scan3_kernel(int* __restrict__ cnt,
                                                    const int* __restrict__ bsum)
{
    int i = blockIdx.x * 256 + threadIdx.x;
    cnt[i] += bsum[blockIdx.x];
}

__global__ __launch_bounds__(256) void scatter_perm_kernel(
    const int* __restrict__ dst, int* __restrict__ cursor,
    int* __restrict__ perm, int E)
{
    int i = blockIdx.x * 256 + threadIdx.x;
    if (i < E) {
        int p = atomicAdd(&cursor[dst[i]], 1);
        perm[p] = i;
    }
}
// after scatter: cursor[v] == rowptr[v+1]

// ===========================================================================
// Weight image (pre-swizzled): img[l][kt][n][s*8+j] = W[kt*32+(s^SW(n))*8+j][n]
// ===========================================================================
__global__ __launch_bounds__(256)
void build_wimg_kernel(const float* __restrict__ W, bf16* __restrict__ img,
                       int K, int KT, int L)
{
    long idx = (long)blockIdx.x * 256 + threadIdx.x;
    long tot = (long)L * KT * 8192;
    if (idx >= tot) return;
    int l  = (int)(idx / ((long)KT * 8192));
    int r  = (int)(idx % ((long)KT * 8192));
    int kt = r >> 13;
    int r2 = r & 8191;
    int n  = r2 >> 5;      // 0..255
    int s  = (r2 >> 3) & 3; // stored slot
    int j  = r2 & 7;
    int k  = kt * 32 + ((s ^ SW(n)) * 8) + j;
    float v = (k < K) ? W[((long)l * K + k) * HID + n] : 0.f;
    img[idx] = f2bf(v);
}

// ===========================================================================
// Message GEMM (MFMA bf16): 512 thr, BM=128 BN=256, rows = CSR-permuted edges
// A = [ h[src] (k<256) || relu(ef@We+be) recomputed (k>=256) ]
// ===========================================================================
__global__ __launch_bounds__(512)
void msg_gemm3(const bf16* __restrict__ h_, const float* __restrict__ ef,
               const float* __restrict__ We, const float* __restrict__ be,
               const int* __restrict__ src, const int* __restrict__ perm,
               const float* __restrict__ W, const bf16* __restrict__ Wimg,
               const float* __restrict__ bias, bf16* __restrict__ mout)
{
    __shared__ __align__(16) short As[128 * 32];
    __shared__ __align__(16) short Bs[256 * 32];
    __shared__ int   srcL[128];
    __shared__ int   edgeL[128];
    __shared__ float efL[128][9];

    const int  t  = threadIdx.x;
    const long bm = (long)blockIdx.x * 128;

    if (t < 128) {
        int eg = perm[bm + t];
        edgeL[t] = eg;
        srcL[t]  = src[eg];
    }
    __syncthreads();
    for (int i = t; i < 128 * 9; i += 512) {
        int r = i / 9, qq = i % 9;
        efL[r][qq] = ef[(long)edgeL[r] * 9 + qq];
    }
    __syncthreads();

    floatx4 acc[4][4];
#pragma unroll
    for (int i = 0; i < 4; ++i)
#pragma unroll
        for (int j = 0; j < 4; ++j) acc[i][j] = (floatx4){0.f, 0.f, 0.f, 0.f};

    const int w = t >> 6, lane = t & 63;
    const int fr = lane & 15, q = lane >> 4;
    const int wm = (w & 1) * 64, wn = (w >> 1) * 64;
    const int arow = t >> 2, akg = t & 3;    // A-staging: 1 slot/thread

    for (int kt = 0; kt < 16; ++kt) {
        const int k0 = kt * 32;
        // ---- A stage (128x32): plain vector load -> swizzled ds_write_b128 ----
        {
            const int kk = k0 + akg * 8;
            short8 pk;
            if (kk < HID) {
                pk = *(const short8*)((const short*)h_ +
                                      ((long)srcL[arow] * HID + kk));
            } else {
                const int kc = kk - HID;
                float s[8];
#pragma unroll
                for (int j = 0; j < 8; ++j) s[j] = be[kc + j];
#pragma unroll
                for (int qq = 0; qq < 9; ++qq) {
                    const float efv = efL[arow][qq];
#pragma unroll
                    for (int j = 0; j < 8; ++j)
                        s[j] = fmaf(efv, We[qq * HID + kc + j], s[j]);
                }
#pragma unroll
                for (int j = 0; j < 8; ++j) pk[j] = (short)f2us(fmaxf(s[j], 0.f));
            }
            *(short8*)&As[arow * 32 + (akg ^ SW(arow)) * 8] = pk;
        }
        // ---- B stage (256x32): coalesced glds16 from pre-swizzled image ----
        if (Wimg) {
            const short* base = (const short*)Wimg + (long)kt * 8192;
#pragma unroll
            for (int j = 0; j < 2; ++j) {
                const int chunk = w * 2 + j;   // 16 chunks x 1024 B
                glds16(base + chunk * 512 + lane * 8, (char*)Bs + chunk * 1024);
            }
        } else {
#pragma unroll
            for (int cc = 0; cc < 2; ++cc) {
                const int slot = t + cc * 512;
                const int n    = slot >> 2;
                const int kg   = slot & 3;
                const int kk   = k0 + kg * 8;
                short8 pk;
#pragma unroll
                for (int j = 0; j < 8; ++j)
                    pk[j] = (short)f2us(W[(long)(kk + j) * HID + n]);
                *(short8*)&Bs[n * 32 + (kg ^ SW(n)) * 8] = pk;
            }
        }
        __syncthreads();
        short8 af[4], bf8[4];
#pragma unroll
        for (int mt = 0; mt < 4; ++mt) {
            const int r = wm + mt * 16 + fr;
            af[mt] = *(const short8*)&As[r * 32 + (q ^ SW(r)) * 8];
        }
#pragma unroll
        for (int nt = 0; nt < 4; ++nt) {
            const int r = wn + nt * 16 + fr;
            bf8[nt] = *(const short8*)&Bs[r * 32 + (q ^ SW(r)) * 8];
        }
#pragma unroll
        for (int mt = 0; mt < 4; ++mt)
#pragma unroll
            for (int nt = 0; nt < 4; ++nt)
                acc[mt][nt] = __builtin_amdgcn_mfma_f32_16x16x32_bf16(
                    af[mt], bf8[nt], acc[mt][nt], 0, 0, 0);
        __syncthreads();
    }

#pragma unroll
    for (int nt = 0; nt < 4; ++nt) {
        const int col = wn + nt * 16 + fr;
        const float bv = bias[col];
#pragma unroll
        for (int mt = 0; mt < 4; ++mt)
#pragma unroll
            for (int reg = 0; reg < 4; ++reg) {
                const long row = bm + wm + mt * 16 + q * 4 + reg;
                mout[row * HID + col] = f2bf(fmaxf(acc[mt][nt][reg] + bv, 0.f));
            }
    }
}

// ===========================================================================
// Update GEMM (MFMA bf16): 512 thr, BM=128 BN=256, rows = nodes, K=256
// A = CSR segment-sum of mbuf. Epilogue: h = LN(h_old + relu(acc+bias)) fused.
// ===========================================================================
__global__ __launch_bounds__(512)
void upd_gemm3(const bf16* __restrict__ mbuf, const int* __restrict__ cursor,
               const float* __restrict__ W, const bf16* __restrict__ Wimg,
               const float* __restrict__ bias,
               const float* __restrict__ lng, const float* __restrict__ lnb,
               bf16* __restrict__ h_)
{
    __shared__ __align__(16) short As[128 * 32];
    __shared__ __align__(16) short Bs[256 * 32];
    __shared__ int   rpL[129];
    __shared__ float redS[128][4];
    __shared__ float redS2[128][4];

    const int  t  = threadIdx.x;
    const long bm = (long)blockIdx.x * 128;

    if (t < 128) rpL[t + 1] = cursor[bm + t];
    if (t == 0)  rpL[0] = (bm == 0) ? 0 : cursor[bm - 1];
    __syncthreads();

    floatx4 acc[4][4];
#pragma unroll
    for (int i = 0; i < 4; ++i)
#pragma unroll
        for (int j = 0; j < 4; ++j) acc[i][j] = (floatx4){0.f, 0.f, 0.f, 0.f};

    const int w = t >> 6, lane = t & 63;
    const int fr = lane & 15, q = lane >> 4;
    const int wm = (w & 1) * 64, wn = (w >> 1) * 64;
    const int arow = t >> 2, akg = t & 3;

    for (int kt = 0; kt < 8; ++kt) {
        const int k0 = kt * 32;
        // ---- A: CSR segment-sum of m ----
        {
            const int kk = k0 + akg * 8;
            float s[8] = {0.f, 0.f, 0.f, 0.f, 0.f, 0.f, 0.f, 0.f};
            const int j1 = rpL[arow + 1];
            for (int j = rpL[arow]; j < j1; ++j) {
                const short8 mv = *(const short8*)((const short*)mbuf +
                                                   ((long)j * HID + kk));
#pragma unroll
                for (int x = 0; x < 8; ++x) s[x] += us2f((unsigned short)mv[x]);
            }
            short8 pk;
#pragma unroll
            for (int x = 0; x < 8; ++x) pk[x] = (short)f2us(s[x]);
            *(short8*)&As[arow * 32 + (akg ^ SW(arow)) * 8] = pk;
        }
        // ---- B ----
        if (Wimg) {
            const short* base = (const short*)Wimg + (long)kt * 8192;
#pragma unroll
            for (int j = 0; j < 2; ++j) {
                const int chunk = w * 2 + j;
                glds16(base + chunk * 512 + lane * 8, (char*)Bs + chunk * 1024);
            }
        } else {
#pragma unroll
            for (int cc = 0; cc < 2; ++cc) {
                const int slot = t + cc * 512;
                const int n    = slot >> 2;
                const int kg   = slot & 3;
                const int kk   = k0 + kg * 8;
                short8 pk;
#pragma unroll
                for (int j = 0; j < 8; ++j)
                    pk[j] = (short)f2us(W[(long)(kk + j) * HID + n]);
                *(short8*)&Bs[n * 32 + (kg ^ SW(n)) * 8] = pk;
            }
        }
        __syncthreads();
        short8 af[4], bf8[4];
#pragma unroll
        for (int mt = 0; mt < 4; ++mt) {
            const int r = wm + mt * 16 + fr;
            af[mt] = *(const short8*)&As[r * 32 + (q ^ SW(r)) * 8];
        }
#pragma unroll
        for (int nt = 0; nt < 4; ++nt) {
            const int r = wn + nt * 16 + fr;
            bf8[nt] = *(const short8*)&Bs[r * 32 + (q ^ SW(r)) * 8];
        }
#pragma unroll
        for (int mt = 0; mt < 4; ++mt)
#pragma unroll
            for (int nt = 0; nt < 4; ++nt)
                acc[mt][nt] = __builtin_amdgcn_mfma_f32_16x16x32_bf16(
                    af[mt], bf8[nt], acc[mt][nt], 0, 0, 0);
        __syncthreads();
    }

    // ---- fused residual + LayerNorm epilogue ----
    const int wnIdx = w >> 1;
#pragma unroll
    for (int mt = 0; mt < 4; ++mt)
#pragma unroll
        for (int reg = 0; reg < 4; ++reg) {
            const int  lrow = wm + mt * 16 + q * 4 + reg;
            const long row  = bm + lrow;
            float ps = 0.f, ps2 = 0.f;
#pragma unroll
            for (int nt = 0; nt < 4; ++nt) {
                const int col = wn + nt * 16 + fr;
                float v = bf2f(h_[row * HID + col]) +
                          fmaxf(acc[mt][nt][reg] + bias[col], 0.f);
                acc[mt][nt][reg] = v;
                ps  += v;
                ps2 += v * v;
            }
#pragma unroll
            for (int m = 1; m < 16; m <<= 1) {
                ps  += __shfl_xor(ps, m);
                ps2 += __shfl_xor(ps2, m);
            }
            if (fr == 0) { redS[lrow][wnIdx] = ps; redS2[lrow][wnIdx] = ps2; }
        }
    __syncthreads();
#pragma unroll
    for (int mt = 0; mt < 4; ++mt)
#pragma unroll
        for (int reg = 0; reg < 4; ++reg) {
            const int  lrow = wm + mt * 16 + q * 4 + reg;
            const long row  = bm + lrow;
            const float ts  = redS[lrow][0] + redS[lrow][1] +
                              redS[lrow][2] + redS[lrow][3];
            const float ts2 = redS2[lrow][0] + redS2[lrow][1] +
                              redS2[lrow][2] + redS2[lrow][3];
            const float mu  = ts * (1.f / 256.f);
            const float var = ts2 * (1.f / 256.f) - mu * mu;
            const float rs  = rsqrtf(var + 1e-5f);
#pragma unroll
            for (int nt = 0; nt < 4; ++nt) {
                const int col = wn + nt * 16 + fr;
                const float y = (acc[mt][nt][reg] - mu) * rs * lng[col] + lnb[col];
                h_[row * HID + col] = f2bf(y);
            }
        }
}

// ===========================================================================
// Node encoder (MFMA bf16): 512 thr, h = relu(nf @ Wn + bn), K 69->96
// ===========================================================================
__global__ __launch_bounds__(512)
void enc_gemm3(const float* __restrict__ nf, const bf16* __restrict__ Wimg,
               const float* __restrict__ bias, bf16* __restrict__ h_)
{
    __shared__ __align__(16) short As[128 * 32];
    __shared__ __align__(16) short Bs[256 * 32];

    const int  t  = threadIdx.x;
    const long bm = (long)blockIdx.x * 128;

    floatx4 acc[4][4];
#pragma unroll
    for (int i = 0; i < 4; ++i)
#pragma unroll
        for (int j = 0; j < 4; ++j) acc[i][j] = (floatx4){0.f, 0.f, 0.f, 0.f};

    const int w = t >> 6, lane = t & 63;
    const int fr = lane & 15, q = lane >> 4;
    const int wm = (w & 1) * 64, wn = (w >> 1) * 64;
    const int arow = t >> 2, akg = t & 3;

    for (int kt = 0; kt < 3; ++kt) {
        const int k0 = kt * 32;
        {
            const int kk = k0 + akg * 8;
            short8 pk;
#pragma unroll
            for (int j = 0; j < 8; ++j) {
                const int k = kk + j;
                pk[j] = (short)f2us((k < 69) ? nf[(bm + arow) * 69 + k] : 0.f);
            }
            *(short8*)&As[arow * 32 + (akg ^ SW(arow)) * 8] = pk;
        }
        const short* base = (const short*)Wimg + (long)kt * 8192;
#pragma unroll
        for (int j = 0; j < 2; ++j) {
            const int chunk = w * 2 + j;
            glds16(base + chunk * 512 + lane * 8, (char*)Bs + chunk * 1024);
        }
        __syncthreads();
        short8 af[4], bf8[4];
#pragma unroll
        for (int mt = 0; mt < 4; ++mt) {
            const int r = wm + mt * 16 + fr;
            af[mt] = *(const short8*)&As[r * 32 + (q ^ SW(r)) * 8];
        }
#pragma unroll
        for (int nt = 0; nt < 4; ++nt) {
            const int r = wn + nt * 16 + fr;
            bf8[nt] = *(const short8*)&Bs[r * 32 + (q ^ SW(r)) * 8];
        }
#pragma unroll
        for (int mt = 0; mt < 4; ++mt)
#pragma unroll
            for (int nt = 0; nt < 4; ++nt)
                acc[mt][nt] = __builtin_amdgcn_mfma_f32_16x16x32_bf16(
                    af[mt], bf8[nt], acc[mt][nt], 0, 0, 0);
        __syncthreads();
    }

#pragma unroll
    for (int nt = 0; nt < 4; ++nt) {
        const int col = wn + nt * 16 + fr;
        const float bv = bias[col];
#pragma unroll
        for (int mt = 0; mt < 4; ++mt)
#pragma unroll
            for (int reg = 0; reg < 4; ++reg) {
                const long row = bm + wm + mt * 16 + q * 4 + reg;
                h_[row * HID + col] = f2bf(fmaxf(acc[mt][nt][reg] + bv, 0.f));
            }
    }
}

// ===========================================================================
// SIMT fp32 GEMM (FiLM / head / encoder fallback)
// ===========================================================================
struct PlainF32 {
    const float* A; int lda;
    __device__ float operator()(int r, int k) const { return A[(long)r * lda + k]; }
};
struct CtxF32 {
    const float* ctx; const int* pid;
    __device__ float operator()(int r, int k) const {
        return ctx[(long)pid[r] * CTXD + k];
    }
};
struct StoreF32 {
    float* C; int ldc; int relu;
    __device__ void operator()(int r, int c, const float* v) const {
        float4 o;
        o.x = v[0]; o.y = v[1]; o.z = v[2]; o.w = v[3];
        if (relu) {
            o.x = fmaxf(o.x, 0.f); o.y = fmaxf(o.y, 0.f);
            o.z = fmaxf(o.z, 0.f); o.w = fmaxf(o.w, 0.f);
        }
        *(float4*)&C[(long)r * ldc + c] = o;
    }
};
struct StoreBf16Relu {
    bf16* C;
    __device__ void operator()(int r, int c, const float* v) const {
        bf16 tmp[4];
#pragma unroll
        for (int j = 0; j < 4; ++j) tmp[j] = f2bf(fmaxf(v[j], 0.f));
        *(ushort4*)&C[(long)r * HID + c] = *(const ushort4*)tmp;
    }
};

template <typename Loader, typename Epi>
__global__ __launch_bounds__(256)
void gemm_tiled(Loader loader, const float* __restrict__ W,
                const float* __restrict__ bias, Epi epi, int M, int K, int Nc)
{
    constexpr int BM = 64, BN = 64, BK = 16;
    __shared__ __align__(16) float As[BK][BM + 4];
    __shared__ __align__(16) float Ws[BK][BN];

    const int bm = blockIdx.x * BM;
    const int bn = blockIdx.y * BN;
    const int t  = threadIdx.x;
    const int arow = t >> 2, akq = (t & 3) * 4;
    const int wn = t & 63, wk0 = t >> 6;
    const int tx = t & 15, ty = t >> 4;

    float acc[4][4] = {};
    const int ntiles = (K + BK - 1) / BK;
    for (int kt = 0; kt < ntiles; ++kt) {
        const int k0 = kt * BK;
#pragma unroll
        for (int i = 0; i < 4; ++i) {
            int k = k0 + akq + i;
            As[akq + i][arow] = (k < K) ? loader(bm + arow, k) : 0.f;
        }
#pragma unroll
        for (int i = 0; i < 4; ++i) {
            int kr = wk0 + i * 4;
            int k  = k0 + kr;
            Ws[kr][wn] = (k < K) ? W[(long)k * Nc + bn + wn] : 0.f;
        }
        __syncthreads();
#pragma unroll
        for (int kk = 0; kk < BK; ++kk) {
            float4 a = *(const float4*)&As[kk][ty * 4];
            float4 b = *(const float4*)&Ws[kk][tx * 4];
            float av[4] = {a.x, a.y, a.z, a.w};
            float bv[4] = {b.x, b.y, b.z, b.w};
#pragma unroll
            for (int i = 0; i < 4; ++i)
#pragma unroll
                for (int j = 0; j < 4; ++j) acc[i][j] += av[i] * bv[j];
        }
        __syncthreads();
    }
#pragma unroll
    for (int i = 0; i < 4; ++i) {
        const int row = bm + ty * 4 + i;
        const int col = bn + tx * 4;
        float v[4];
#pragma unroll
        for (int j = 0; j < 4; ++j) v[j] = acc[i][j] + bias[col + j];
        epi(row, col, v);
    }
}

// ===========================================================================
// LN (fp32, FiLM) / readout / FiLM / head
// ===========================================================================
__global__ __launch_bounds__(256)
void ln_f32_relu_kernel(float* __restrict__ x, const float* __restrict__ g,
                        const float* __restrict__ bb)
{
    const long row = blockIdx.x;
    const int  j   = threadIdx.x;
    float v = x[row * HID + j];
    float s = v, s2 = v * v;
#pragma unroll
    for (int o = 32; o > 0; o >>= 1) {
        s  += __shfl_down(s, o);
        s2 += __shfl_down(s2, o);
    }
    __shared__ float red[2][4];
    const int wid = j >> 6, lane = j & 63;
    if (lane == 0) { red[0][wid] = s; red[1][wid] = s2; }
    __syncthreads();
    float ts  = red[0][0] + red[0][1] + red[0][2] + red[0][3];
    float ts2 = red[1][0] + red[1][1] + red[1][2] + red[1][3];
    float mu  = ts * (1.f / 256.f);
    float var = ts2 * (1.f / 256.f) - mu * mu;
    float y = (v - mu) * rsqrtf(var + 1e-5f) * g[j] + bb[j];
    x[row * HID + j] = fmaxf(y, 0.f);
}

__device__ int lower_bound_i(const int* __restrict__ arr, int n, int val)
{
    int lo = 0, hi = n;
    while (lo < hi) {
        int mid = (lo + hi) >> 1;
        if (arr[mid] < val) lo = mid + 1; else hi = mid;
    }
    return lo;
}

__global__ __launch_bounds__(256)
void readout_kernel(const bf16* __restrict__ h, const int* __restrict__ b,
                    float* __restrict__ gout, int Nn)
{
    const int gidx = blockIdx.x;
    const int j    = threadIdx.x;
    const int lo   = lower_bound_i(b, Nn, gidx);
    const int hi   = lower_bound_i(b, Nn, gidx + 1);
    float s = 0.f, mx = -INFINITY;
    for (int n = lo; n < hi; ++n) {
        float v = bf2f(h[(long)n * HID + j]);
        s += v;
        mx = fmaxf(mx, v);
    }
    const int cnt = hi - lo;
    gout[(long)gidx * FEAT + j]       = s / fmaxf((float)cnt, 1.f);
    gout[(long)gidx * FEAT + HID + j] = (cnt > 0) ? mx : 0.f;
}

__global__ __launch_bounds__(256)
void film_mod_kernel(const float* __restrict__ gamma, float* __restrict__ g,
                     const float* __restrict__ beta, int n)
{
    int i = blockIdx.x * 256 + threadIdx.x;
    if (i < n) g[i] = gamma[i] * g[i] + beta[i];
}

__global__ __launch_bounds__(256)
void final_dot_kernel(const float* __restrict__ ph, const float* __restrict__ w,
                      const float* __restrict__ b2, float* __restrict__ out)
{
    const int row  = blockIdx.x * 4 + (threadIdx.x >> 6);
    const int lane = threadIdx.x & 63;
    float s = 0.f;
#pragma unroll
    for (int k = lane; k < HID; k += 64)
        s += ph[(long)row * HID + k] * w[k];
#pragma unroll
    for (int o = 32; o > 0; o >>= 1) s += __shfl_down(s, o);
    if (lane == 0) out[row] = s + b2[0];
}

__global__ void diag_out_kernel(float* out, int n, float wsmb)
{
    int i = blockIdx.x * 256 + threadIdx.x;
    if (i < n) out[i] = (i == 0) ? wsmb : 0.f;
}

// ===========================================================================
// launcher
// ===========================================================================
extern "C" void kernel_launch(void* const* d_in, const int* in_sizes, int n_in,
                              void* d_out, int out_size, void* d_ws, size_t ws_size,
                              hipStream_t stream)
{
    const int N = 131072, E = 262144, B = 4096;

    const float* nf   = (const float*)d_in[0];
    const int*   ei   = (const int*)  d_in[1];
    const float* ef   = (const float*)d_in[2];
    const int*   bidx = (const int*)  d_in[3];
    const int*   pid  = (const int*)  d_in[4];
    const float* Wn   = (const float*)d_in[5];
    const float* bn   = (const float*)d_in[6];
    const float* We   = (const float*)d_in[7];
    const float* be   = (const float*)d_in[8];
    const float* Wm   = (const float*)d_in[9];
    const float* bm   = (const float*)d_in[10];
    const float* Wu   = (const float*)d_in[11];
    const float* bu   = (const float*)d_in[12];
    const float* lng  = (const float*)d_in[13];
    const float* lnb  = (const float*)d_in[14];
    const float* ctx  = (const float*)d_in[15];
    const float* gW1  = (const float*)d_in[16];
    const float* gb1  = (const float*)d_in[17];
    const float* glng = (const float*)d_in[18];
    const float* glnb = (const float*)d_in[19];
    const float* gW2  = (const float*)d_in[20];
    const float* gb2  = (const float*)d_in[21];
    const float* bW1  = (const float*)d_in[22];
    const float* bb1  = (const float*)d_in[23];
    const float* blng = (const float*)d_in[24];
    const float* blnb = (const float*)d_in[25];
    const float* bW2  = (const float*)d_in[26];
    const float* bb2  = (const float*)d_in[27];
    const float* pW1  = (const float*)d_in[28];
    const float* pb1  = (const float*)d_in[29];
    const float* pW2  = (const float*)d_in[30];
    const float* pb2  = (const float*)d_in[31];

    const int* src = ei;
    const int* dst = ei + E;
    float* out = (float*)d_out;

    const size_t hB    = (size_t)N * HID * sizeof(bf16);   //  64 MiB
    const size_t mB    = (size_t)E * HID * sizeof(bf16);   // 128 MiB
    const size_t curB  = (size_t)N * 4;                    // 512 KiB
    const size_t permB = (size_t)E * 4;                    //   1 MiB
    const size_t bsumB = 2048 * 4;
    const size_t wmImgB = (size_t)NLAYER * 16 * 8192 * 2;  //   1 MiB
    const size_t wuImgB = (size_t)NLAYER * 8  * 8192 * 2;  // 512 KiB
    const size_t wnImgB = (size_t)3 * 8192 * 2;            //  48 KiB

    const size_t needBase = hB + mB + curB + permB + bsumB;       // ~193.5 MiB
    const size_t needFull = needBase + wmImgB + wuImgB + wnImgB;  // ~195.1 MiB

    if (ws_size < needBase) {
        diag_out_kernel<<<dim3((B + 255) / 256), dim3(256), 0, stream>>>(
            out, B, (float)(ws_size >> 20));
        return;
    }
    const bool haveImg = ws_size >= needFull;

    char* p = (char*)d_ws;
    bf16* h      = (bf16*)p;  p += hB;
    bf16* mbuf   = (bf16*)p;  p += mB;
    int*  cursor = (int*)p;   p += curB;
    int*  perm   = (int*)p;   p += permB;
    int*  bsum   = (int*)p;   p += bsumB;
    bf16* wmImg = nullptr; bf16* wuImg = nullptr; bf16* wnImg = nullptr;
    if (haveImg) {
        wmImg = (bf16*)p; p += wmImgB;
        wuImg = (bf16*)p; p += wuImgB;
        wnImg = (bf16*)p; p += wnImgB;
    }

    // FiLM scratch aliases mbuf (dead after layers)
    float* gbuf  = (float*)mbuf;            // B*512
    float* t1    = gbuf  + (long)B * FEAT;  // B*256
    float* t2    = t1    + (long)B * HID;   // B*256
    float* gamma = t2    + (long)B * HID;   // B*512
    float* beta  = gamma + (long)B * FEAT;  // B*512
    float* ph    = beta  + (long)B * FEAT;  // B*256

    dim3 blk(256), blk5(512);

    // --- CSR build ---
    hipMemsetAsync(cursor, 0, curB, stream);
    hist_kernel<<<dim3(E / 256), blk, 0, stream>>>(dst, cursor, E);
    scan1_kernel<<<dim3(N / 256), blk, 0, stream>>>(cursor, bsum);
    scan2_kernel<<<dim3(1), dim3(512), 0, stream>>>(bsum);
    scan3_kernel<<<dim3(N / 256), blk, 0, stream>>>(cursor, bsum);
    scatter_perm_kernel<<<dim3(E / 256), blk, 0, stream>>>(dst, cursor, perm, E);

    // --- weight images (bf16, pre-swizzled LDS layout) ---
    if (haveImg) {
        build_wimg_kernel<<<dim3((NLAYER * 16 * 8192 + 255) / 256), blk, 0, stream>>>(
            Wm, wmImg, 2 * HID, 16, NLAYER);
        build_wimg_kernel<<<dim3((NLAYER * 8 * 8192 + 255) / 256), blk, 0, stream>>>(
            Wu, wuImg, HID, 8, NLAYER);
        build_wimg_kernel<<<dim3((3 * 8192 + 255) / 256), blk, 0, stream>>>(
            Wn, wnImg, 69, 3, 1);
    }

    // --- node encoder ---
    if (haveImg) {
        enc_gemm3<<<dim3(N / 128), blk5, 0, stream>>>(nf, wnImg, bn, h);
    } else {
        gemm_tiled<<<dim3(N / 64, HID / 64), blk, 0, stream>>>(
            PlainF32{nf, 69}, Wn, bn, StoreBf16Relu{h}, N, 69, HID);
    }

    // --- message-passing layers ---
    for (int l = 0; l < NLAYER; ++l) {
        const float* Wml  = Wm  + (long)l * 2 * HID * HID;
        const float* bml  = bm  + (long)l * HID;
        const float* Wul  = Wu  + (long)l * HID * HID;
        const float* bul  = bu  + (long)l * HID;
        const float* lngl = lng + (long)l * HID;
        const float* lnbl = lnb + (long)l * HID;
        const bf16* wmI = haveImg ? wmImg + (long)l * 16 * 8192 : nullptr;
        const bf16* wuI = haveImg ? wuImg + (long)l * 8 * 8192 : nullptr;

        msg_gemm3<<<dim3(E / 128), blk5, 0, stream>>>(
            h, ef, We, be, src, perm, Wml, wmI, bml, mbuf);
        upd_gemm3<<<dim3(N / 128), blk5, 0, stream>>>(
            mbuf, cursor, Wul, wuI, bul, lngl, lnbl, h);
    }

    // --- readout ---
    readout_kernel<<<dim3(B), blk, 0, stream>>>(h, bidx, gbuf, N);

    // --- FiLM gamma / beta ---
    gemm_tiled<<<dim3(B / 64, HID / 64), blk, 0, stream>>>(
        CtxF32{ctx, pid}, gW1, gb1, StoreF32{t1, HID, 0}, B, CTXD, HID);
    ln_f32_relu_kernel<<<dim3(B), blk, 0, stream>>>(t1, glng, glnb);
    gemm_tiled<<<dim3(B / 64, FEAT / 64), blk, 0, stream>>>(
        PlainF32{t1, HID}, gW2, gb2, StoreF32{gamma, FEAT, 0}, B, HID, FEAT);

    gemm_tiled<<<dim3(B / 64, HID / 64), blk, 0, stream>>>(
        CtxF32{ctx, pid}, bW1, bb1, StoreF32{t2, HID, 0}, B, CTXD, HID);
    ln_f32_relu_kernel<<<dim3(B), blk, 0, stream>>>(t2, blng, blnb);
    gemm_tiled<<<dim3(B / 64, FEAT / 64), blk, 0, stream>>>(
        PlainF32{t2, HID}, bW2, bb2, StoreF32{beta, FEAT, 0}, B, HID, FEAT);

    // --- FiLM modulation + head ---
    film_mod_kernel<<<dim3((B * FEAT + 255) / 256), blk, 0, stream>>>(
        gamma, gbuf, beta, B * FEAT);
    gemm_tiled<<<dim3(B / 64, HID / 64), blk, 0, stream>>>(
        PlainF32{gbuf, FEAT}, pW1, pb1, StoreF32{ph, HID, 1}, B, FEAT, HID);
    final_dot_kernel<<<dim3(B / 4), blk, 0, stream>>>(ph, pW2, pb2, out);
}

// Round 7
// 1948.848 us; speedup vs baseline: 1.4447x; 1.0281x over previous
//
#include <hip/hip_runtime.h>
#include <hip/hip_bf16.h>
#include <math.h>

#define HID 256
#define CTXD 128
#define FEAT 512
#define NLAYER 4

// LDS slot swizzle: row stride is 32 shorts (64 B); rows 2 apart alias banks,
// so XOR the 16B k-group slot with (row>>1)&3 -> worst case 2-way (free, m136).
#define SW(n) (((n) >> 1) & 3)

typedef __hip_bfloat16 bf16;
typedef __attribute__((ext_vector_type(8))) short short8;
typedef __attribute__((ext_vector_type(4))) float floatx4;

__device__ __forceinline__ float bf2f(bf16 x) { return __bfloat162float(x); }
__device__ __forceinline__ bf16 f2bf(float x) { return __float2bfloat16(x); }
__device__ __forceinline__ float us2f(unsigned short u) {
    union { unsigned u; float f; } c; c.u = ((unsigned)u) << 16; return c.f;
}
__device__ __forceinline__ unsigned short f2us(float f) {
    bf16 b = f2bf(f); return *(unsigned short*)&b;
}

// async global->LDS, 16 B/lane, COALESCED addresses only (wave-uniform LDS base)
__device__ __forceinline__ void glds16(const void* g, void* l) {
    __builtin_amdgcn_global_load_lds(
        (__attribute__((address_space(1))) void*)g,
        (__attribute__((address_space(3))) void*)l, 16, 0, 0);
}

// ===========================================================================
// CSR build: counting sort of edges by dst
// ===========================================================================
__global__ __launch_bounds__(256) void hist_kernel(const int* __restrict__ dst,
                                                   int* __restrict__ cnt, int E)
{
    int i = blockIdx.x * 256 + threadIdx.x;
    if (i < E) atomicAdd(&cnt[dst[i]], 1);
}

__global__ __launch_bounds__(256) void scan1_kernel(int* __restrict__ cnt,
                                                    int* __restrict__ bsum)
{
    __shared__ int sd[256];
    const int t = threadIdx.x;
    const int i = blockIdx.x * 256 + t;
    int v = cnt[i];
    sd[t] = v;
    __syncthreads();
    for (int o = 1; o < 256; o <<= 1) {
        int x = (t >= o) ? sd[t - o] : 0;
        __syncthreads();
        sd[t] += x;
        __syncthreads();
    }
    cnt[i] = sd[t] - v;
    if (t == 255) bsum[blockIdx.x] = sd[255];
}

__global__ void scan2_kernel(int* __restrict__ bsum)  // 1 block, 512 threads
{
    __shared__ int sd[512];
    const int t = threadIdx.x;
    int v = bsum[t];
    sd[t] = v;
    __syncthreads();
    for (int o = 1; o < 512; o <<= 1) {
        int x = (t >= o) ? sd[t - o] : 0;
        __syncthreads();
        sd[t] += x;
        __syncthreads();
    }
    bsum[t] = sd[t] - v;
}

__global__ __launch_bounds__(256) void scan3_kernel(int* __restrict__ cnt,
                                                    const int* __restrict__ bsum)
{
    int i = blockIdx.x * 256 + threadIdx.x;
    cnt[i] += bsum[blockIdx.x];
}

__global__ __launch_bounds__(256) void scatter_perm_kernel(
    const int* __restrict__ dst, int* __restrict__ cursor,
    int* __restrict__ perm, int E)
{
    int i = blockIdx.x * 256 + threadIdx.x;
    if (i < E) {
        int p = atomicAdd(&cursor[dst[i]], 1);
        perm[p] = i;
    }
}
// after scatter: cursor[v] == rowptr[v+1]

// ===========================================================================
// Weight image (pre-swizzled): img[l][kt][n][s*8+j] = W[kt*32+(s^SW(n))*8+j][n]
// ===========================================================================
__global__ __launch_bounds__(256)
void build_wimg_kernel(const float* __restrict__ W, bf16* __restrict__ img,
                       int K, int KT, int L)
{
    long idx = (long)blockIdx.x * 256 + threadIdx.x;
    long tot = (long)L * KT * 8192;
    if (idx >= tot) return;
    int l  = (int)(idx / ((long)KT * 8192));
    int r  = (int)(idx % ((long)KT * 8192));
    int kt = r >> 13;
    int r2 = r & 8191;
    int n  = r2 >> 5;      // 0..255
    int s  = (r2 >> 3) & 3; // stored slot
    int j  = r2 & 7;
    int k  = kt * 32 + ((s ^ SW(n)) * 8) + j;
    float v = (k < K) ? W[((long)l * K + k) * HID + n] : 0.f;
    img[idx] = f2bf(v);
}

// ===========================================================================
// Shared K-iteration tail: B stage (glds or fallback), sync, MFMA, sync
// ===========================================================================
__device__ __forceinline__ void kt_tail(
    int kt, const bf16* __restrict__ Wimg, const float* __restrict__ W,
    short* As, short* Bs, floatx4 (&acc)[4][4])
{
    const int t = threadIdx.x;
    const int w = t >> 6, lane = t & 63;
    const int fr = lane & 15, q = lane >> 4;
    const int wm = (w & 1) * 64, wn = (w >> 1) * 64;
    const int k0 = kt * 32;

    if (Wimg) {
        const short* base = (const short*)Wimg + (long)kt * 8192;
#pragma unroll
        for (int j = 0; j < 2; ++j) {
            const int chunk = w * 2 + j;   // 16 chunks x 1024 B
            glds16(base + chunk * 512 + lane * 8, (char*)Bs + chunk * 1024);
        }
    } else {
#pragma unroll
        for (int cc = 0; cc < 2; ++cc) {
            const int slot = t + cc * 512;
            const int n    = slot >> 2;
            const int kg   = slot & 3;
            const int kk   = k0 + kg * 8;
            short8 pk;
#pragma unroll
            for (int j = 0; j < 8; ++j)
                pk[j] = (short)f2us(W[(long)(kk + j) * HID + n]);
            *(short8*)&Bs[n * 32 + (kg ^ SW(n)) * 8] = pk;
        }
    }
    __syncthreads();
    short8 af[4], bf8[4];
#pragma unroll
    for (int mt = 0; mt < 4; ++mt) {
        const int r = wm + mt * 16 + fr;
        af[mt] = *(const short8*)&As[r * 32 + (q ^ SW(r)) * 8];
    }
#pragma unroll
    for (int nt = 0; nt < 4; ++nt) {
        const int r = wn + nt * 16 + fr;
        bf8[nt] = *(const short8*)&Bs[r * 32 + (q ^ SW(r)) * 8];
    }
#pragma unroll
    for (int mt = 0; mt < 4; ++mt)
#pragma unroll
        for (int nt = 0; nt < 4; ++nt)
            acc[mt][nt] = __builtin_amdgcn_mfma_f32_16x16x32_bf16(
                af[mt], bf8[nt], acc[mt][nt], 0, 0, 0);
    __syncthreads();
}

// ===========================================================================
// Message GEMM (MFMA bf16): 512 thr, BM=128 BN=256, rows = CSR-permuted edges
// A = [ h[src] (k<256, REGISTER-STASHED upfront) || relu(ef@We+be) (k>=256) ]
// The stash removes the per-kt random-gather latency from the K-loop chain:
// all 8 independent 16B gathers issue back-to-back before the loop.
// ===========================================================================
__global__ __launch_bounds__(512)
void msg_gemm4(const bf16* __restrict__ h_, const float* __restrict__ ef,
               const float* __restrict__ We, const float* __restrict__ be,
               const int* __restrict__ src, const int* __restrict__ perm,
               const float* __restrict__ W, const bf16* __restrict__ Wimg,
               const float* __restrict__ bias, bf16* __restrict__ mout)
{
    __shared__ __align__(16) short As[128 * 32];
    __shared__ __align__(16) short Bs[256 * 32];
    __shared__ int   srcL[128];
    __shared__ int   edgeL[128];
    __shared__ float efL[128][9];

    const int  t  = threadIdx.x;
    const long bm = (long)blockIdx.x * 128;

    if (t < 128) {
        int eg = perm[bm + t];
        edgeL[t] = eg;
        srcL[t]  = src[eg];
    }
    __syncthreads();
    for (int i = t; i < 128 * 9; i += 512) {
        int r = i / 9, qq = i % 9;
        efL[r][qq] = ef[(long)edgeL[r] * 9 + qq];
    }

    floatx4 acc[4][4];
#pragma unroll
    for (int i = 0; i < 4; ++i)
#pragma unroll
        for (int j = 0; j < 4; ++j) acc[i][j] = (floatx4){0.f, 0.f, 0.f, 0.f};

    const int w = t >> 6, lane = t & 63;
    const int fr = lane & 15, q = lane >> 4;
    const int wm = (w & 1) * 64, wn = (w >> 1) * 64;
    const int arow = t >> 2, akg = t & 3;    // A-staging: 1 slot/thread
    const int aslot = arow * 32 + (akg ^ SW(arow)) * 8;

    // ---- register stash: all 8 A-h slices issued upfront (independent) ----
    const long hbase = (long)srcL[arow] * HID + akg * 8;
    short8 stash[8];
#pragma unroll
    for (int kt = 0; kt < 8; ++kt)
        stash[kt] = *(const short8*)((const short*)h_ + hbase + kt * 32);
    __syncthreads();   // efL ready (also spaces the stash loads)

    // ---- kts 0..7: A from stash (no in-loop global dependency) ----
#pragma unroll
    for (int kt = 0; kt < 8; ++kt) {
        *(short8*)&As[aslot] = stash[kt];
        kt_tail(kt, Wimg, W, As, Bs, acc);
    }
    // ---- kts 8..15: A = relu(ef@We+be) recomputed (VALU only) ----
    for (int kt = 8; kt < 16; ++kt) {
        const int kc = (kt - 8) * 32 + akg * 8;
        float s[8];
#pragma unroll
        for (int j = 0; j < 8; ++j) s[j] = be[kc + j];
#pragma unroll
        for (int qq = 0; qq < 9; ++qq) {
            const float efv = efL[arow][qq];
#pragma unroll
            for (int j = 0; j < 8; ++j)
                s[j] = fmaf(efv, We[qq * HID + kc + j], s[j]);
        }
        short8 pk;
#pragma unroll
        for (int j = 0; j < 8; ++j) pk[j] = (short)f2us(fmaxf(s[j], 0.f));
        *(short8*)&As[aslot] = pk;
        kt_tail(kt, Wimg, W, As, Bs, acc);
    }

#pragma unroll
    for (int nt = 0; nt < 4; ++nt) {
        const int col = wn + nt * 16 + fr;
        const float bv = bias[col];
#pragma unroll
        for (int mt = 0; mt < 4; ++mt)
#pragma unroll
            for (int reg = 0; reg < 4; ++reg) {
                const long row = bm + wm + mt * 16 + q * 4 + reg;
                mout[row * HID + col] = f2bf(fmaxf(acc[mt][nt][reg] + bv, 0.f));
            }
    }
}

// ===========================================================================
// Update GEMM (MFMA bf16): 512 thr, BM=128 BN=256, rows = nodes, K=256
// A = CSR segment-sum of mbuf. Epilogue: h = LN(h_old + relu(acc+bias)) fused.
// ===========================================================================
__global__ __launch_bounds__(512)
void upd_gemm3(const bf16* __restrict__ mbuf, const int* __restrict__ cursor,
               const float* __restrict__ W, const bf16* __restrict__ Wimg,
               const float* __restrict__ bias,
               const float* __restrict__ lng, const float* __restrict__ lnb,
               bf16* __restrict__ h_)
{
    __shared__ __align__(16) short As[128 * 32];
    __shared__ __align__(16) short Bs[256 * 32];
    __shared__ int   rpL[129];
    __shared__ float redS[128][4];
    __shared__ float redS2[128][4];

    const int  t  = threadIdx.x;
    const long bm = (long)blockIdx.x * 128;

    if (t < 128) rpL[t + 1] = cursor[bm + t];
    if (t == 0)  rpL[0] = (bm == 0) ? 0 : cursor[bm - 1];
    __syncthreads();

    floatx4 acc[4][4];
#pragma unroll
    for (int i = 0; i < 4; ++i)
#pragma unroll
        for (int j = 0; j < 4; ++j) acc[i][j] = (floatx4){0.f, 0.f, 0.f, 0.f};

    const int w = t >> 6, lane = t & 63;
    const int fr = lane & 15, q = lane >> 4;
    const int wm = (w & 1) * 64, wn = (w >> 1) * 64;
    const int arow = t >> 2, akg = t & 3;
    const int aslot = arow * 32 + (akg ^ SW(arow)) * 8;

    for (int kt = 0; kt < 8; ++kt) {
        const int kk = kt * 32 + akg * 8;
        // ---- A: CSR segment-sum of m (sequential mbuf rows, L2-friendly) ----
        {
            float s[8] = {0.f, 0.f, 0.f, 0.f, 0.f, 0.f, 0.f, 0.f};
            const int j1 = rpL[arow + 1];
            for (int j = rpL[arow]; j < j1; ++j) {
                const short8 mv = *(const short8*)((const short*)mbuf +
                                                   ((long)j * HID + kk));
#pragma unroll
                for (int x = 0; x < 8; ++x) s[x] += us2f((unsigned short)mv[x]);
            }
            short8 pk;
#pragma unroll
            for (int x = 0; x < 8; ++x) pk[x] = (short)f2us(s[x]);
            *(short8*)&As[aslot] = pk;
        }
        kt_tail(kt, Wimg, W, As, Bs, acc);
    }

    // ---- fused residual + LayerNorm epilogue ----
    const int wnIdx = w >> 1;
#pragma unroll
    for (int mt = 0; mt < 4; ++mt)
#pragma unroll
        for (int reg = 0; reg < 4; ++reg) {
            const int  lrow = wm + mt * 16 + q * 4 + reg;
            const long row  = bm + lrow;
            float ps = 0.f, ps2 = 0.f;
#pragma unroll
            for (int nt = 0; nt < 4; ++nt) {
                const int col = wn + nt * 16 + fr;
                float v = bf2f(h_[row * HID + col]) +
                          fmaxf(acc[mt][nt][reg] + bias[col], 0.f);
                acc[mt][nt][reg] = v;
                ps  += v;
                ps2 += v * v;
            }
#pragma unroll
            for (int m = 1; m < 16; m <<= 1) {
                ps  += __shfl_xor(ps, m);
                ps2 += __shfl_xor(ps2, m);
            }
            if (fr == 0) { redS[lrow][wnIdx] = ps; redS2[lrow][wnIdx] = ps2; }
        }
    __syncthreads();
#pragma unroll
    for (int mt = 0; mt < 4; ++mt)
#pragma unroll
        for (int reg = 0; reg < 4; ++reg) {
            const int  lrow = wm + mt * 16 + q * 4 + reg;
            const long row  = bm + lrow;
            const float ts  = redS[lrow][0] + redS[lrow][1] +
                              redS[lrow][2] + redS[lrow][3];
            const float ts2 = redS2[lrow][0] + redS2[lrow][1] +
                              redS2[lrow][2] + redS2[lrow][3];
            const float mu  = ts * (1.f / 256.f);
            const float var = ts2 * (1.f / 256.f) - mu * mu;
            const float rs  = rsqrtf(var + 1e-5f);
#pragma unroll
            for (int nt = 0; nt < 4; ++nt) {
                const int col = wn + nt * 16 + fr;
                const float y = (acc[mt][nt][reg] - mu) * rs * lng[col] + lnb[col];
                h_[row * HID + col] = f2bf(y);
            }
        }
}

// ===========================================================================
// Node encoder (MFMA bf16): 512 thr, h = relu(nf @ Wn + bn), K 69->96
// ===========================================================================
__global__ __launch_bounds__(512)
void enc_gemm3(const float* __restrict__ nf, const bf16* __restrict__ Wimg,
               const float* __restrict__ bias, bf16* __restrict__ h_)
{
    __shared__ __align__(16) short As[128 * 32];
    __shared__ __align__(16) short Bs[256 * 32];

    const int  t  = threadIdx.x;
    const long bm = (long)blockIdx.x * 128;

    floatx4 acc[4][4];
#pragma unroll
    for (int i = 0; i < 4; ++i)
#pragma unroll
        for (int j = 0; j < 4; ++j) acc[i][j] = (floatx4){0.f, 0.f, 0.f, 0.f};

    const int w = t >> 6, lane = t & 63;
    const int fr = lane & 15, q = lane >> 4;
    const int wm = (w & 1) * 64, wn = (w >> 1) * 64;
    const int arow = t >> 2, akg = t & 3;
    const int aslot = arow * 32 + (akg ^ SW(arow)) * 8;

    for (int kt = 0; kt < 3; ++kt) {
        const int kk = kt * 32 + akg * 8;
        short8 pk;
#pragma unroll
        for (int j = 0; j < 8; ++j) {
            const int k = kk + j;
            pk[j] = (short)f2us((k < 69) ? nf[(bm + arow) * 69 + k] : 0.f);
        }
        *(short8*)&As[aslot] = pk;
        kt_tail(kt, Wimg, nullptr, As, Bs, acc);
    }

#pragma unroll
    for (int nt = 0; nt < 4; ++nt) {
        const int col = wn + nt * 16 + fr;
        const float bv = bias[col];
#pragma unroll
        for (int mt = 0; mt < 4; ++mt)
#pragma unroll
            for (int reg = 0; reg < 4; ++reg) {
                const long row = bm + wm + mt * 16 + q * 4 + reg;
                h_[row * HID + col] = f2bf(fmaxf(acc[mt][nt][reg] + bv, 0.f));
            }
    }
}

// ===========================================================================
// SIMT fp32 GEMM (FiLM / head / encoder fallback)
// ===========================================================================
struct PlainF32 {
    const float* A; int lda;
    __device__ float operator()(int r, int k) const { return A[(long)r * lda + k]; }
};
struct CtxF32 {
    const float* ctx; const int* pid;
    __device__ float operator()(int r, int k) const {
        return ctx[(long)pid[r] * CTXD + k];
    }
};
struct StoreF32 {
    float* C; int ldc; int relu;
    __device__ void operator()(int r, int c, const float* v) const {
        float4 o;
        o.x = v[0]; o.y = v[1]; o.z = v[2]; o.w = v[3];
        if (relu) {
            o.x = fmaxf(o.x, 0.f); o.y = fmaxf(o.y, 0.f);
            o.z = fmaxf(o.z, 0.f); o.w = fmaxf(o.w, 0.f);
        }
        *(float4*)&C[(long)r * ldc + c] = o;
    }
};
struct StoreBf16Relu {
    bf16* C;
    __device__ void operator()(int r, int c, const float* v) const {
        bf16 tmp[4];
#pragma unroll
        for (int j = 0; j < 4; ++j) tmp[j] = f2bf(fmaxf(v[j], 0.f));
        *(ushort4*)&C[(long)r * HID + c] = *(const ushort4*)tmp;
    }
};

template <typename Loader, typename Epi>
__global__ __launch_bounds__(256)
void gemm_tiled(Loader loader, const float* __restrict__ W,
                const float* __restrict__ bias, Epi epi, int M, int K, int Nc)
{
    constexpr int BM = 64, BN = 64, BK = 16;
    __shared__ __align__(16) float As[BK][BM + 4];
    __shared__ __align__(16) float Ws[BK][BN];

    const int bm = blockIdx.x * BM;
    const int bn = blockIdx.y * BN;
    const int t  = threadIdx.x;
    const int arow = t >> 2, akq = (t & 3) * 4;
    const int wn = t & 63, wk0 = t >> 6;
    const int tx = t & 15, ty = t >> 4;

    float acc[4][4] = {};
    const int ntiles = (K + BK - 1) / BK;
    for (int kt = 0; kt < ntiles; ++kt) {
        const int k0 = kt * BK;
#pragma unroll
        for (int i = 0; i < 4; ++i) {
            int k = k0 + akq + i;
            As[akq + i][arow] = (k < K) ? loader(bm + arow, k) : 0.f;
        }
#pragma unroll
        for (int i = 0; i < 4; ++i) {
            int kr = wk0 + i * 4;
            int k  = k0 + kr;
            Ws[kr][wn] = (k < K) ? W[(long)k * Nc + bn + wn] : 0.f;
        }
        __syncthreads();
#pragma unroll
        for (int kk = 0; kk < BK; ++kk) {
            float4 a = *(const float4*)&As[kk][ty * 4];
            float4 b = *(const float4*)&Ws[kk][tx * 4];
            float av[4] = {a.x, a.y, a.z, a.w};
            float bv[4] = {b.x, b.y, b.z, b.w};
#pragma unroll
            for (int i = 0; i < 4; ++i)
#pragma unroll
                for (int j = 0; j < 4; ++j) acc[i][j] += av[i] * bv[j];
        }
        __syncthreads();
    }
#pragma unroll
    for (int i = 0; i < 4; ++i) {
        const int row = bm + ty * 4 + i;
        const int col = bn + tx * 4;
        float v[4];
#pragma unroll
        for (int j = 0; j < 4; ++j) v[j] = acc[i][j] + bias[col + j];
        epi(row, col, v);
    }
}

// ===========================================================================
// LN (fp32, FiLM) / readout / FiLM / head
// ===========================================================================
__global__ __launch_bounds__(256)
void ln_f32_relu_kernel(float* __restrict__ x, const float* __restrict__ g,
                        const float* __restrict__ bb)
{
    const long row = blockIdx.x;
    const int  j   = threadIdx.x;
    float v = x[row * HID + j];
    float s = v, s2 = v * v;
#pragma unroll
    for (int o = 32; o > 0; o >>= 1) {
        s  += __shfl_down(s, o);
        s2 += __shfl_down(s2, o);
    }
    __shared__ float red[2][4];
    const int wid = j >> 6, lane = j & 63;
    if (lane == 0) { red[0][wid] = s; red[1][wid] = s2; }
    __syncthreads();
    float ts  = red[0][0] + red[0][1] + red[0][2] + red[0][3];
    float ts2 = red[1][0] + red[1][1] + red[1][2] + red[1][3];
    float mu  = ts * (1.f / 256.f);
    float var = ts2 * (1.f / 256.f) - mu * mu;
    float y = (v - mu) * rsqrtf(var + 1e-5f) * g[j] + bb[j];
    x[row * HID + j] = fmaxf(y, 0.f);
}

__device__ int lower_bound_i(const int* __restrict__ arr, int n, int val)
{
    int lo = 0, hi = n;
    while (lo < hi) {
        int mid = (lo + hi) >> 1;
        if (arr[mid] < val) lo = mid + 1; else hi = mid;
    }
    return lo;
}

__global__ __launch_bounds__(256)
void readout_kernel(const bf16* __restrict__ h, const int* __restrict__ b,
                    float* __restrict__ gout, int Nn)
{
    const int gidx = blockIdx.x;
    const int j    = threadIdx.x;
    const int lo   = lower_bound_i(b, Nn, gidx);
    const int hi   = lower_bound_i(b, Nn, gidx + 1);
    float s = 0.f, mx = -INFINITY;
    for (int n = lo; n < hi; ++n) {
        float v = bf2f(h[(long)n * HID + j]);
        s += v;
        mx = fmaxf(mx, v);
    }
    const int cnt = hi - lo;
    gout[(long)gidx * FEAT + j]       = s / fmaxf((float)cnt, 1.f);
    gout[(long)gidx * FEAT + HID + j] = (cnt > 0) ? mx : 0.f;
}

__global__ __launch_bounds__(256)
void film_mod_kernel(const float* __restrict__ gamma, float* __restrict__ g,
                     const float* __restrict__ beta, int n)
{
    int i = blockIdx.x * 256 + threadIdx.x;
    if (i < n) g[i] = gamma[i] * g[i] + beta[i];
}

__global__ __launch_bounds__(256)
void final_dot_kernel(const float* __restrict__ ph, const float* __restrict__ w,
                      const float* __restrict__ b2, float* __restrict__ out)
{
    const int row  = blockIdx.x * 4 + (threadIdx.x >> 6);
    const int lane = threadIdx.x & 63;
    float s = 0.f;
#pragma unroll
    for (int k = lane; k < HID; k += 64)
        s += ph[(long)row * HID + k] * w[k];
#pragma unroll
    for (int o = 32; o > 0; o >>= 1) s += __shfl_down(s, o);
    if (lane == 0) out[row] = s + b2[0];
}

__global__ void diag_out_kernel(float* out, int n, float wsmb)
{
    int i = blockIdx.x * 256 + threadIdx.x;
    if (i < n) out[i] = (i == 0) ? wsmb : 0.f;
}

// ===========================================================================
// launcher
// ===========================================================================
extern "C" void kernel_launch(void* const* d_in, const int* in_sizes, int n_in,
                              void* d_out, int out_size, void* d_ws, size_t ws_size,
                              hipStream_t stream)
{
    const int N = 131072, E = 262144, B = 4096;

    const float* nf   = (const float*)d_in[0];
    const int*   ei   = (const int*)  d_in[1];
    const float* ef   = (const float*)d_in[2];
    const int*   bidx = (const int*)  d_in[3];
    const int*   pid  = (const int*)  d_in[4];
    const float* Wn   = (const float*)d_in[5];
    const float* bn   = (const float*)d_in[6];
    const float* We   = (const float*)d_in[7];
    const float* be   = (const float*)d_in[8];
    const float* Wm   = (const float*)d_in[9];
    const float* bm   = (const float*)d_in[10];
    const float* Wu   = (const float*)d_in[11];
    const float* bu   = (const float*)d_in[12];
    const float* lng  = (const float*)d_in[13];
    const float* lnb  = (const float*)d_in[14];
    const float* ctx  = (const float*)d_in[15];
    const float* gW1  = (const float*)d_in[16];
    const float* gb1  = (const float*)d_in[17];
    const float* glng = (const float*)d_in[18];
    const float* glnb = (const float*)d_in[19];
    const float* gW2  = (const float*)d_in[20];
    const float* gb2  = (const float*)d_in[21];
    const float* bW1  = (const float*)d_in[22];
    const float* bb1  = (const float*)d_in[23];
    const float* blng = (const float*)d_in[24];
    const float* blnb = (const float*)d_in[25];
    const float* bW2  = (const float*)d_in[26];
    const float* bb2  = (const float*)d_in[27];
    const float* pW1  = (const float*)d_in[28];
    const float* pb1  = (const float*)d_in[29];
    const float* pW2  = (const float*)d_in[30];
    const float* pb2  = (const float*)d_in[31];

    const int* src = ei;
    const int* dst = ei + E;
    float* out = (float*)d_out;

    const size_t hB    = (size_t)N * HID * sizeof(bf16);   //  64 MiB
    const size_t mB    = (size_t)E * HID * sizeof(bf16);   // 128 MiB
    const size_t curB  = (size_t)N * 4;                    // 512 KiB
    const size_t permB = (size_t)E * 4;                    //   1 MiB
    const size_t bsumB = 2048 * 4;
    const size_t wmImgB = (size_t)NLAYER * 16 * 8192 * 2;  //   1 MiB
    const size_t wuImgB = (size_t)NLAYER * 8  * 8192 * 2;  // 512 KiB
    const size_t wnImgB = (size_t)3 * 8192 * 2;            //  48 KiB

    const size_t needBase = hB + mB + curB + permB + bsumB;       // ~193.5 MiB
    const size_t needFull = needBase + wmImgB + wuImgB + wnImgB;  // ~195.1 MiB

    if (ws_size < needBase) {
        diag_out_kernel<<<dim3((B + 255) / 256), dim3(256), 0, stream>>>(
            out, B, (float)(ws_size >> 20));
        return;
    }
    const bool haveImg = ws_size >= needFull;

    char* p = (char*)d_ws;
    bf16* h      = (bf16*)p;  p += hB;
    bf16* mbuf   = (bf16*)p;  p += mB;
    int*  cursor = (int*)p;   p += curB;
    int*  perm   = (int*)p;   p += permB;
    int*  bsum   = (int*)p;   p += bsumB;
    bf16* wmImg = nullptr; bf16* wuImg = nullptr; bf16* wnImg = nullptr;
    if (haveImg) {
        wmImg = (bf16*)p; p += wmImgB;
        wuImg = (bf16*)p; p += wuImgB;
        wnImg = (bf16*)p; p += wnImgB;
    }

    // FiLM scratch aliases mbuf (dead after layers)
    float* gbuf  = (float*)mbuf;            // B*512
    float* t1    = gbuf  + (long)B * FEAT;  // B*256
    float* t2    = t1    + (long)B * HID;   // B*256
    float* gamma = t2    + (long)B * HID;   // B*512
    float* beta  = gamma + (long)B * FEAT;  // B*512
    float* ph    = beta  + (long)B * FEAT;  // B*256

    dim3 blk(256), blk5(512);

    // --- CSR build ---
    hipMemsetAsync(cursor, 0, curB, stream);
    hist_kernel<<<dim3(E / 256), blk, 0, stream>>>(dst, cursor, E);
    scan1_kernel<<<dim3(N / 256), blk, 0, stream>>>(cursor, bsum);
    scan2_kernel<<<dim3(1), dim3(512), 0, stream>>>(bsum);
    scan3_kernel<<<dim3(N / 256), blk, 0, stream>>>(cursor, bsum);
    scatter_perm_kernel<<<dim3(E / 256), blk, 0, stream>>>(dst, cursor, perm, E);

    // --- weight images (bf16, pre-swizzled LDS layout) ---
    if (haveImg) {
        build_wimg_kernel<<<dim3((NLAYER * 16 * 8192 + 255) / 256), blk, 0, stream>>>(
            Wm, wmImg, 2 * HID, 16, NLAYER);
        build_wimg_kernel<<<dim3((NLAYER * 8 * 8192 + 255) / 256), blk, 0, stream>>>(
            Wu, wuImg, HID, 8, NLAYER);
        build_wimg_kernel<<<dim3((3 * 8192 + 255) / 256), blk, 0, stream>>>(
            Wn, wnImg, 69, 3, 1);
    }

    // --- node encoder ---
    if (haveImg) {
        enc_gemm3<<<dim3(N / 128), blk5, 0, stream>>>(nf, wnImg, bn, h);
    } else {
        gemm_tiled<<<dim3(N / 64, HID / 64), blk, 0, stream>>>(
            PlainF32{nf, 69}, Wn, bn, StoreBf16Relu{h}, N, 69, HID);
    }

    // --- message-passing layers ---
    for (int l = 0; l < NLAYER; ++l) {
        const float* Wml  = Wm  + (long)l * 2 * HID * HID;
        const float* bml  = bm  + (long)l * HID;
        const float* Wul  = Wu  + (long)l * HID * HID;
        const float* bul  = bu  + (long)l * HID;
        const float* lngl = lng + (long)l * HID;
        const float* lnbl = lnb + (long)l * HID;
        const bf16* wmI = haveImg ? wmImg + (long)l * 16 * 8192 : nullptr;
        const bf16* wuI = haveImg ? wuImg + (long)l * 8 * 8192 : nullptr;

        msg_gemm4<<<dim3(E / 128), blk5, 0, stream>>>(
            h, ef, We, be, src, perm, Wml, wmI, bml, mbuf);
        upd_gemm3<<<dim3(N / 128), blk5, 0, stream>>>(
            mbuf, cursor, Wul, wuI, bul, lngl, lnbl, h);
    }

    // --- readout ---
    readout_kernel<<<dim3(B), blk, 0, stream>>>(h, bidx, gbuf, N);

    // --- FiLM gamma / beta ---
    gemm_tiled<<<dim3(B / 64, HID / 64), blk, 0, stream>>>(
        CtxF32{ctx, pid}, gW1, gb1, StoreF32{t1, HID, 0}, B, CTXD, HID);
    ln_f32_relu_kernel<<<dim3(B), blk, 0, stream>>>(t1, glng, glnb);
    gemm_tiled<<<dim3(B / 64, FEAT / 64), blk, 0, stream>>>(
        PlainF32{t1, HID}, gW2, gb2, StoreF32{gamma, FEAT, 0}, B, HID, FEAT);

    gemm_tiled<<<dim3(B / 64, HID / 64), blk, 0, stream>>>(
        CtxF32{ctx, pid}, bW1, bb1, StoreF32{t2, HID, 0}, B, CTXD, HID);
    ln_f32_relu_kernel<<<dim3(B), blk, 0, stream>>>(t2, blng, blnb);
    gemm_tiled<<<dim3(B / 64, FEAT / 64), blk, 0, stream>>>(
        PlainF32{t2, HID}, bW2, bb2, StoreF32{beta, FEAT, 0}, B, HID, FEAT);

    // --- FiLM modulation + head ---
    film_mod_kernel<<<dim3((B * FEAT + 255) / 256), blk, 0, stream>>>(
        gamma, gbuf, beta, B * FEAT);
    gemm_tiled<<<dim3(B / 64, HID / 64), blk, 0, stream>>>(
        PlainF32{gbuf, FEAT}, pW1, pb1, StoreF32{ph, HID, 1}, B, FEAT, HID);
    final_dot_kernel<<<dim3(B / 4), blk, 0, stream>>>(ph, pW2, pb2, out);
}